// Round 12
// baseline (75.207 us; speedup 1.0000x reference)
//
#include <hip/hip_runtime.h>

// ROI head matcher. R12: cut the LDS pipe term (the largest in the R4/R11
// pipe model: ~11.6 us LDS vs ~7 us VALU) while keeping high TLP and the
// chain-free reduction.
//   - P=2 proposals per lane: one ds_read_b128 per GT serves two IoU chains;
//     GT area recomputed in 3 VALU ops (no ds_read_b32). LDS total ~3.9 us.
//   - Tournament tree per group of 4 GTs (depth-2 + one carried merge).
//   - Block = 256 thr = 4 waves; block owns 128 proposals; wave w scans GT
//     quarter [32w,32w+32). 1563 blocks x 4 waves = 24.4 waves/CU, fully
//     co-resident (~6 blocks/CU vs 8-block cap) -> no serial block rounds.
// All pairings/merges ascending-index with strict '>' -> jnp.argmax
// first-index tie semantics exact (validated absmax 0, R2-R11).
//
// Pair compare (exact Dekker):
//   i1/u1 > i2/u2  <=>  (p1+e1) > (p2+e2),  e = fmaf(a,b,-p)
// One IEEE divide in the epilogue reproduces best_match_iou bit-exactly.

#define IOU_THRESHOLD 0.5f
#define LOW_BG_IOU 0.1f
#define BLOCK 256
#define PROPS 128   // proposals per block (P=2 per lane)

struct Cand { float i, u; int g; };

__device__ __forceinline__ Cand merge_up(Cand a, Cand b) {
    // b has strictly higher indices; replaces a only if strictly greater.
    float p1 = b.i * a.u;
    float e1 = fmaf(b.i, a.u, -p1);
    float p2 = a.i * b.u;
    float e2 = fmaf(a.i, b.u, -p2);
    bool gt = (p1 - p2) > (e2 - e1);
    Cand r;
    r.i = gt ? b.i : a.i;
    r.u = gt ? b.u : a.u;
    r.g = gt ? b.g : a.g;
    return r;
}

// 11-op IoU numerator/denominator, reference rounding.
__device__ __forceinline__ void iou_nd(float4 gb, float garea, float4 P,
                                       float areaP, float& i, float& u) {
    float x1 = fmaxf(gb.x, P.x);
    float y1 = fmaxf(gb.y, P.y);
    float x2 = fminf(gb.z, P.z);
    float y2 = fminf(gb.w, P.w);
    float iw = fmaxf(x2 - x1, 0.0f);
    float ih = fmaxf(y2 - y1, 0.0f);
    i = iw * ih;
    u = (garea + areaP) - i;
}

__global__ __launch_bounds__(BLOCK, 6) void roi_match_kernel(
    const float* __restrict__ proposals,   // [N,4]
    const float* __restrict__ gt_boxes,    // [128,4]
    const int*   __restrict__ gt_labels,   // [128]
    float* __restrict__ out,               // [N] labels then [N,4] boxes
    int N)
{
#pragma clang fp contract(off)
    __shared__ float4 s_gt[128];
    __shared__ float  s_lab[128];
    __shared__ float4 s_part[4][PROPS];    // [gt-quarter][proposal slot]

    const int tid  = threadIdx.x;
    const int wave = tid >> 6;
    const int lane = tid & 63;
    const int base = blockIdx.x * PROPS;

    if (tid < 128) {
        s_gt[tid]  = ((const float4*)gt_boxes)[tid];
        s_lab[tid] = (float)gt_labels[tid];
    }
    __syncthreads();

    // Two proposals per lane; all 4 waves cover the same 128 proposals.
    const int n0 = base + lane;
    const int n1 = base + 64 + lane;
    const int c0 = n0 < N ? n0 : N - 1;    // clamp loads; writes guarded
    const int c1 = n1 < N ? n1 : N - 1;
    const float4 P0 = ((const float4*)proposals)[c0];
    const float4 P1 = ((const float4*)proposals)[c1];
    const float a0 = (P0.z - P0.x) * (P0.w - P0.y);
    const float a1 = (P1.z - P1.x) * (P1.w - P1.y);

    const int gbase = wave * 32;           // this wave's GT quarter
    Cand best0 = {0.0f, 1.0f, gbase};      // iou-0 sentinel at first index
    Cand best1 = {0.0f, 1.0f, gbase};

#pragma unroll 2
    for (int grp = 0; grp < 8; ++grp) {    // 8 groups of 4 GTs
        const int g0 = gbase + grp * 4;

        float4 gb0 = s_gt[g0 + 0];
        float4 gb1 = s_gt[g0 + 1];
        float4 gb2 = s_gt[g0 + 2];
        float4 gb3 = s_gt[g0 + 3];
        // area in VALU (3 ops each) -> no ds_read_b32, reference rounding
        float ar0 = (gb0.z - gb0.x) * (gb0.w - gb0.y);
        float ar1 = (gb1.z - gb1.x) * (gb1.w - gb1.y);
        float ar2 = (gb2.z - gb2.x) * (gb2.w - gb2.y);
        float ar3 = (gb3.z - gb3.x) * (gb3.w - gb3.y);

        // proposal 0: 4 independent IoUs -> depth-2 tree -> carried merge
        {
            float i0, u0, i1, u1, i2, u2, i3, u3;
            iou_nd(gb0, ar0, P0, a0, i0, u0);
            iou_nd(gb1, ar1, P0, a0, i1, u1);
            iou_nd(gb2, ar2, P0, a0, i2, u2);
            iou_nd(gb3, ar3, P0, a0, i3, u3);
            Cand c01 = merge_up(Cand{i0, u0, g0 + 0}, Cand{i1, u1, g0 + 1});
            Cand c23 = merge_up(Cand{i2, u2, g0 + 2}, Cand{i3, u3, g0 + 3});
            best0 = merge_up(best0, merge_up(c01, c23));
        }
        // proposal 1 (independent chain -> ILP)
        {
            float i0, u0, i1, u1, i2, u2, i3, u3;
            iou_nd(gb0, ar0, P1, a1, i0, u0);
            iou_nd(gb1, ar1, P1, a1, i1, u1);
            iou_nd(gb2, ar2, P1, a1, i2, u2);
            iou_nd(gb3, ar3, P1, a1, i3, u3);
            Cand c01 = merge_up(Cand{i0, u0, g0 + 0}, Cand{i1, u1, g0 + 1});
            Cand c23 = merge_up(Cand{i2, u2, g0 + 2}, Cand{i3, u3, g0 + 3});
            best1 = merge_up(best1, merge_up(c01, c23));
        }
    }

    s_part[wave][lane]      = make_float4(best0.i, best0.u, __int_as_float(best0.g), 0.0f);
    s_part[wave][lane + 64] = make_float4(best1.i, best1.u, __int_as_float(best1.g), 0.0f);
    __syncthreads();

    // Combine: threads 0..127 each own one proposal; quarters ascending.
    if (tid < PROPS) {
        const int n = base + tid;
        if (n < N) {
            float4 v0 = s_part[0][tid];
            Cand b = {v0.x, v0.y, __float_as_int(v0.z)};
#pragma unroll
            for (int q = 1; q < 4; ++q) {
                float4 v = s_part[q][tid];
                b = merge_up(b, Cand{v.x, v.y, __float_as_int(v.z)});
            }
            float iou = b.i / b.u;         // IEEE div == reference max

            float lab;
            if (iou < LOW_BG_IOU)          lab = -1.0f;        // ignored
            else if (iou < IOU_THRESHOLD)  lab = 0.0f;         // background
            else                           lab = s_lab[b.g];

            out[n] = lab;
            ((float4*)(out + N))[n] = s_gt[b.g];  // 800000 B offset, aligned
        }
    }
}

extern "C" void kernel_launch(void* const* d_in, const int* in_sizes, int n_in,
                              void* d_out, int out_size, void* d_ws, size_t ws_size,
                              hipStream_t stream) {
    const float* proposals = (const float*)d_in[0];
    const float* gt_boxes  = (const float*)d_in[1];
    const int*   gt_labels = (const int*)d_in[2];
    float* out = (float*)d_out;

    int N = in_sizes[0] / 4;               // 200000
    int blocks = (N + PROPS - 1) / PROPS;  // 1563

    roi_match_kernel<<<blocks, BLOCK, 0, stream>>>(proposals, gt_boxes,
                                                   gt_labels, out, N);
}